// Round 5
// baseline (1084.515 us; speedup 1.0000x reference)
//
#include <hip/hip_runtime.h>
#include <math.h>

#define HIDDEN 512
#define INPUT  64
#define NB     64     // distinct batch rows (8 trials are bit-identical replicas)
#define NT     8
#define WARM   100
#define RESP   400
#define ALPHA  0.1f

#define NREGC  23     // half8 chunks per thread pinned in VGPRs (92 VGPRs)
#define NLDSC  9      // half8 chunks per thread in LDS (144 KB)

typedef _Float16 half8  __attribute__((ext_vector_type(8)));
typedef _Float16 half2v __attribute__((ext_vector_type(2)));

#if defined(__has_builtin)
#  if __has_builtin(__builtin_amdgcn_fdot2)
#    define HAS_FDOT2 1
#  endif
#endif

__device__ __forceinline__ void dot8(half8 w, half8 s, float& a0, float& a1) {
#ifdef HAS_FDOT2
  a0 = __builtin_amdgcn_fdot2(__builtin_shufflevector(w, w, 0, 1),
                              __builtin_shufflevector(s, s, 0, 1), a0, false);
  a1 = __builtin_amdgcn_fdot2(__builtin_shufflevector(w, w, 2, 3),
                              __builtin_shufflevector(s, s, 2, 3), a1, false);
  a0 = __builtin_amdgcn_fdot2(__builtin_shufflevector(w, w, 4, 5),
                              __builtin_shufflevector(s, s, 4, 5), a0, false);
  a1 = __builtin_amdgcn_fdot2(__builtin_shufflevector(w, w, 6, 7),
                              __builtin_shufflevector(s, s, 6, 7), a1, false);
#else
#pragma unroll
  for (int l = 0; l < 8; ++l)
    ((l & 1) ? a1 : a0) = fmaf((float)w[l], (float)s[l], (l & 1) ? a1 : a0);
#endif
}

// w chunk supplied as 4 opaque floats (each = 2 packed f16)
__device__ __forceinline__ void dot8f(float w0, float w1, float w2, float w3,
                                      half8 s, float& a0, float& a1) {
#ifdef HAS_FDOT2
  a0 = __builtin_amdgcn_fdot2(__builtin_bit_cast(half2v, w0),
                              __builtin_shufflevector(s, s, 0, 1), a0, false);
  a1 = __builtin_amdgcn_fdot2(__builtin_bit_cast(half2v, w1),
                              __builtin_shufflevector(s, s, 2, 3), a1, false);
  a0 = __builtin_amdgcn_fdot2(__builtin_bit_cast(half2v, w2),
                              __builtin_shufflevector(s, s, 4, 5), a0, false);
  a1 = __builtin_amdgcn_fdot2(__builtin_bit_cast(half2v, w3),
                              __builtin_shufflevector(s, s, 6, 7), a1, false);
#else
  const float wf[4] = {w0, w1, w2, w3};
#pragma unroll
  for (int p = 0; p < 4; ++p) {
    half2v wp = __builtin_bit_cast(half2v, wf[p]);
    float& a = (p & 1) ? a1 : a0;
    a = fmaf((float)wp[0], (float)s[2 * p], a);
    a = fmaf((float)wp[1], (float)s[2 * p + 1], a);
  }
#endif
}

// Pack W_rec fp32 [j][k] -> f16 Wpk[k>>3][j][8] (coalesced main-kernel loads).
__global__ void convert_w_pack_kernel(const float* __restrict__ W,
                                      _Float16* __restrict__ Wpk) {
  const int t = blockIdx.x * blockDim.x + threadIdx.x;  // HIDDEN*64 threads
  const int kblk = t & 63;
  const int j = t >> 6;
  const float* src = W + (size_t)j * HIDDEN + kblk * 8;
  _Float16* dst = Wpk + ((size_t)kblk * HIDDEN + j) * 8;
#pragma unroll
  for (int l = 0; l < 8; ++l) dst[l] = (_Float16)src[l];
}

// One wg per distinct batch row; 1024 threads = 2 k-halves x 512 j.
// W truly CU-resident: 23/32 chunks pinned in VGPRs (opaque asm defeats
// rematerialization), 9/32 in LDS. Zero global traffic in the step loop.
__launch_bounds__(1024, 4)
__global__ void leaky_rnn_res_kernel(const float* __restrict__ inputs,
                                     const float* __restrict__ W_in,
                                     const float* __restrict__ b_in,
                                     const _Float16* __restrict__ Wpk,
                                     const float* __restrict__ w_out,
                                     const float* __restrict__ b_out,
                                     float* __restrict__ out /*[NB][NT][RESP]*/) {
  const int b = blockIdx.x;
  const int t = threadIdx.x;
  const int j = t & (HIDDEN - 1);
  const int kh = t >> 9;  // 0 or 1

  __shared__ __align__(16) half8 ldsW[NLDSC][1024];   // 144 KB, chunk-major
  __shared__ __align__(16) _Float16 sp_h[HIDDEN];     // softplus(h) as f16
  __shared__ float xin[INPUT];
  __shared__ float redk[HIDDEN];  // upper-k-half partial dots
  __shared__ float wsum[8];       // per-wave w_out.h partials

  // ---- init: W into regs + LDS (coalesced: lanes 16B apart) ----
  const half8* __restrict__ Wp8 =
      (const half8*)Wpk + (size_t)(kh * 32) * HIDDEN + j;
  const float4* __restrict__ Wp4 = (const float4*)Wp8;  // same addresses, 16B units

  float wrf[NREGC * 4];
#pragma unroll
  for (int c = 0; c < NREGC; ++c) {
    float4 v = Wp4[(size_t)c * HIDDEN];
    wrf[4 * c + 0] = v.x;
    wrf[4 * c + 1] = v.y;
    wrf[4 * c + 2] = v.z;
    wrf[4 * c + 3] = v.w;
    // Opaque producer: values can no longer be rematerialized from memory.
    asm volatile("" : "+v"(wrf[4 * c + 0]), "+v"(wrf[4 * c + 1]),
                      "+v"(wrf[4 * c + 2]), "+v"(wrf[4 * c + 3]));
  }
#pragma unroll
  for (int c = 0; c < NLDSC; ++c) ldsW[c][t] = Wp8[(size_t)(NREGC + c) * HIDDEN];

  if (t < INPUT) xin[t] = inputs[b * INPUT + t];
  __syncthreads();  // xin + ldsW visible

  float ic = 0.f, wout = 0.f;
  const float bout = b_out[0];
  if (t < HIDDEN) {
    ic = b_in[j];
    const float* wi = W_in + (size_t)j * INPUT;
#pragma unroll
    for (int i = 0; i < INPUT; ++i) ic = fmaf(xin[i], wi[i], ic);
    wout = w_out[j];
    sp_h[j] = (_Float16)0.6931471805599453f;  // softplus(0)
  }
  float h = 0.f;
  __syncthreads();  // sp_h visible

  const half8* sp8 = ((const half8*)sp_h) + kh * 32;
  float* const ob = out + (size_t)b * (NT * RESP) + (t < NT ? t * RESP : 0);

  for (int step = 0; step < WARM + RESP; ++step) {
    float acc0 = 0.f, acc1 = 0.f;
    // LDS-resident chunks first (ds reads overlap with reg-chunk VALU)
#pragma unroll
    for (int c = 0; c < NLDSC; ++c) {
      half8 w = ldsW[c][t];        // 16B-stride lanes: conflict-free
      half8 s = sp8[NREGC + c];    // wave-uniform broadcast
      dot8(w, s, acc0, acc1);
    }
    // register-pinned chunks
#pragma unroll
    for (int c = 0; c < NREGC; ++c) {
      half8 s = sp8[c];
      dot8f(wrf[4 * c + 0], wrf[4 * c + 1], wrf[4 * c + 2], wrf[4 * c + 3],
            s, acc0, acc1);
    }
    const float acc = acc0 + acc1;

    if (t >= HIDDEN) redk[j] = acc;  // upper k-half publishes partial
    __syncthreads();                 // redk ready; sp_h reads complete

    if (t < HIDDEN) {
      const float rec = acc + redk[j];
      h = h * (1.f - ALPHA) + ALPHA * (rec + ic);
      const float sp = fmaxf(h, 0.f) + log1pf(expf(-fabsf(h)));  // stable softplus
      sp_h[j] = (_Float16)sp;
      if (step >= WARM) {
        float v = h * wout;
#pragma unroll
        for (int off = 32; off > 0; off >>= 1) v += __shfl_down(v, off);
        if ((t & 63) == 0) wsum[t >> 6] = v;
      }
    }
    __syncthreads();  // new sp_h + wsum visible

    if (step >= WARM && t < NT) {
      float o = bout;
#pragma unroll
      for (int w = 0; w < 8; ++w) o += wsum[w];
      const float hz = 1.f / (1.f + expf(-o));
      ob[step - WARM] = hz;  // 8 identical trial copies, one lane each
    }
  }
}

// ---------------- fp32 fallback (round-0 kernel) for tiny ws ----------------
__launch_bounds__(512, 1)
__global__ void leaky_rnn_row_kernel(const float* __restrict__ inputs,
                                     const float* __restrict__ W_in,
                                     const float* __restrict__ b_in,
                                     const float* __restrict__ W_rec,
                                     const float* __restrict__ w_out,
                                     const float* __restrict__ b_out,
                                     float* __restrict__ out) {
  const int b = blockIdx.x;
  const int j = threadIdx.x;
  __shared__ float sp[HIDDEN];
  __shared__ float xin[INPUT];
  __shared__ float red[8];
  if (j < INPUT) xin[j] = inputs[b * INPUT + j];
  __syncthreads();
  float ic = b_in[j];
  const float* wi = W_in + j * INPUT;
#pragma unroll
  for (int i = 0; i < INPUT; ++i) ic = fmaf(xin[i], wi[i], ic);
  const float wout = w_out[j];
  const float bout = b_out[0];
  float h = 0.0f;
  sp[j] = 0.6931471805599453f;
  __syncthreads();
  const float4* __restrict__ Wr = (const float4*)(W_rec + (size_t)j * HIDDEN);
  for (int step = 0; step < WARM + RESP; ++step) {
    float rec = 0.0f;
#pragma unroll 8
    for (int k4 = 0; k4 < HIDDEN / 4; ++k4) {
      float4 w = Wr[k4];
      float4 s = *(const float4*)&sp[4 * k4];
      rec = fmaf(w.x, s.x, rec);
      rec = fmaf(w.y, s.y, rec);
      rec = fmaf(w.z, s.z, rec);
      rec = fmaf(w.w, s.w, rec);
    }
    h = h * (1.0f - ALPHA) + ALPHA * (rec + ic);
    if (step >= WARM) {
      float v = h * wout;
#pragma unroll
      for (int off = 32; off > 0; off >>= 1) v += __shfl_down(v, off);
      if ((j & 63) == 0) red[j >> 6] = v;
    }
    __syncthreads();
    sp[j] = fmaxf(h, 0.0f) + log1pf(expf(-fabsf(h)));
    if (step >= WARM && j == 0) {
      float o = bout;
#pragma unroll
      for (int w = 0; w < 8; ++w) o += red[w];
      const float hz = 1.0f / (1.0f + expf(-o));
      const int s = step - WARM;
      float* obp = out + (size_t)b * (NT * RESP) + s;
#pragma unroll
      for (int tr = 0; tr < NT; ++tr) obp[tr * RESP] = hz;
    }
    __syncthreads();
  }
}

extern "C" void kernel_launch(void* const* d_in, const int* in_sizes, int n_in,
                              void* d_out, int out_size, void* d_ws, size_t ws_size,
                              hipStream_t stream) {
  const float* inputs = (const float*)d_in[0];
  const float* W_in   = (const float*)d_in[1];
  const float* b_in   = (const float*)d_in[2];
  const float* W_rec  = (const float*)d_in[3];
  const float* w_out  = (const float*)d_in[4];
  const float* b_out  = (const float*)d_in[5];
  float* out = (float*)d_out;

  const int nW = HIDDEN * HIDDEN;
  if (ws_size >= (size_t)nW * sizeof(_Float16)) {
    _Float16* Wpk = (_Float16*)d_ws;
    convert_w_pack_kernel<<<dim3(HIDDEN * 64 / 256), dim3(256), 0, stream>>>(W_rec, Wpk);
    leaky_rnn_res_kernel<<<dim3(NB), dim3(2 * HIDDEN), 0, stream>>>(
        inputs, W_in, b_in, Wpk, w_out, b_out, out);
  } else {
    leaky_rnn_row_kernel<<<dim3(NB), dim3(HIDDEN), 0, stream>>>(
        inputs, W_in, b_in, W_rec, w_out, b_out, out);
  }
}